// Round 6
// baseline (169.036 us; speedup 1.0000x reference)
//
#include <hip/hip_runtime.h>

#define DEV __device__ __forceinline__

typedef __attribute__((ext_vector_type(8))) short short8;
typedef __attribute__((ext_vector_type(4))) float f32x4;
typedef __bf16 bf16x8 __attribute__((ext_vector_type(8)));
typedef unsigned int u32;
typedef unsigned short u16;

constexpr int Bb = 2, Ss = 2048, Dd = 1024, Hh = 16, DKc = 64;
constexpr int Kk = 1024;   // inner dim of all projection GEMMs

// log2(e)/8: folds the 1/sqrt(DK) score scale AND the exp->exp2 conversion into Q
#define QSCALE 0.1803368801111204f

// ---- fp32 <-> bf16 (RNE), no hip_bf16 dependency ----
DEV u16 f2bf(float f) {
  u32 u = __builtin_bit_cast(u32, f);
  u32 r = (u + 0x7fffu + ((u >> 16) & 1u)) >> 16;
  return (u16)r;
}

DEV u32 pk_bf16(float lo, float hi) {
  u32 w;
  asm("v_cvt_pk_bf16_f32 %0, %1, %2" : "=v"(w) : "v"(lo), "v"(hi));
  return w;
}

DEV f32x4 mfma16(short8 a, short8 b, f32x4 c) {
  return __builtin_amdgcn_mfma_f32_16x16x32_bf16(
      __builtin_bit_cast(bf16x8, a), __builtin_bit_cast(bf16x8, b), c, 0, 0, 0);
}

DEV void gload_lds16(const u16* g, u16* lds) {
  __builtin_amdgcn_global_load_lds(
      (const __attribute__((address_space(1))) u32*)g,
      (__attribute__((address_space(3))) u32*)lds, 16, 0, 0);
}

// ---------------- fp32 -> bf16 conversion (7 tensors in one launch) ----------------
struct CvtArgs {
  const float* in[7];
  u16* out[7];
  int n[7];
};

__global__ __launch_bounds__(256) void cvt_all(CvtArgs a) {
  int z = blockIdx.z;
  int i = (blockIdx.x * 256 + threadIdx.x) * 4;
  if (i >= a.n[z]) return;
  float4 v = *reinterpret_cast<const float4*>(a.in[z] + i);
  ushort4 o;
  o.x = f2bf(v.x); o.y = f2bf(v.y); o.z = f2bf(v.z); o.w = f2bf(v.w);
  *reinterpret_cast<ushort4*>(a.out[z] + i) = o;
}

// ---------------- GEMM core v2: BM=MT*32 x BN=NT*32, BK=32, triple-buffered ----------
// One s_barrier per K-step; stage issued 2 steps ahead; counted vmcnt keeps the
// next stage's S loads in flight across the barrier (loads get ~2 compute phases).
// LDS tile layout == linear [row][32] (16x32 chunks), 2-way bank alias only.
template<int MT, int NT>
DEV void gemm_core(const u16* __restrict__ A, const u16* __restrict__ Bt,
                   u16* smA, u16* smB, f32x4 (&acc)[MT][NT], int gm0, int gn0) {
  constexpr int NSTEP = Kk / 32;
  constexpr int SA = MT * 1024;            // elements per A buffer
  constexpr int SB = NT * 1024;
  constexpr int S = MT / 2 + NT / 2;       // gloads per thread per stage
  const int tid = threadIdx.x;
  const int w = tid >> 6, l = tid & 63;
  const int g = (l >> 4) & 3, r = l & 15;
  const int wm = w >> 1, wn = w & 1;
  const int srow = l >> 2, scol = (l & 3) * 8;  // 16 rows x 32 cols per 1KB chunk

  auto stage = [&](int buf, int kt) {
    int kb = kt * 32;
#pragma unroll
    for (int cc = 0; cc < MT / 2; ++cc) {
      int c = w + cc * 4;
      gload_lds16(A + (size_t)(gm0 + c * 16 + srow) * Kk + kb + scol,
                  smA + buf * SA + c * 512);
    }
#pragma unroll
    for (int cc = 0; cc < NT / 2; ++cc) {
      int c = w + cc * 4;
      gload_lds16(Bt + (size_t)(gn0 + c * 16 + srow) * Kk + kb + scol,
                  smB + buf * SB + c * 512);
    }
  };

  stage(0, 0);
  stage(1, 1);
  for (int kt = 0; kt < NSTEP; ++kt) {
    const int buf = kt % 3;
    if (kt + 1 < NSTEP) {
      if constexpr (S == 4) asm volatile("s_waitcnt vmcnt(4)" ::: "memory");
      else                  asm volatile("s_waitcnt vmcnt(3)" ::: "memory");
    } else {
      asm volatile("s_waitcnt vmcnt(0)" ::: "memory");
    }
    __builtin_amdgcn_s_barrier();           // stage(kt) visible to all waves
    __builtin_amdgcn_sched_barrier(0);
    if (kt + 2 < NSTEP) stage((kt + 2) % 3, kt + 2);

    short8 af[MT], bf_[NT];
#pragma unroll
    for (int t = 0; t < MT; ++t)
      af[t] = *reinterpret_cast<const short8*>(
          smA + buf * SA + (wm * (MT * 16) + t * 16 + r) * 32 + g * 8);
#pragma unroll
    for (int t = 0; t < NT; ++t)
      bf_[t] = *reinterpret_cast<const short8*>(
          smB + buf * SB + (wn * (NT * 16) + t * 16 + r) * 32 + g * 8);
    __builtin_amdgcn_s_setprio(1);
#pragma unroll
    for (int mt = 0; mt < MT; ++mt)
#pragma unroll
      for (int nt = 0; nt < NT; ++nt)
        acc[mt][nt] = mfma16(af[mt], bf_[nt], acc[mt][nt]);
    __builtin_amdgcn_s_setprio(0);
  }
}

// ---------------- QKV projection: z=0 Q (pre-scaled by QSCALE), z=1 K -> (B,H,S,DK);
// z=2 V -> (B,H,DK,S) ----
__global__ __launch_bounds__(256, 3) void proj_qkv(
    const u16* __restrict__ xq, const u16* __restrict__ xk, const u16* __restrict__ xv,
    const u16* __restrict__ Wq, const u16* __restrict__ Wk, const u16* __restrict__ Wv,
    const float* __restrict__ bq, const float* __restrict__ bk, const float* __restrict__ bv,
    u16* __restrict__ Qh, u16* __restrict__ Kh, u16* __restrict__ Vt) {
  __shared__ u16 smA[3 * 128 * 32], smB[3 * 128 * 32];
  // XCD swizzle: flat id -> xcd*96+pos (768 = 8*96, bijective); groups 12 A-panels/XCD
  const int flat = (blockIdx.z * 32 + blockIdx.y) * 8 + blockIdx.x;
  const int nid = (flat & 7) * 96 + (flat >> 3);
  const int bx = nid & 7, by = (nid >> 3) & 31, z = nid >> 8;
  const u16* A = z == 0 ? xq : (z == 1 ? xk : xv);
  const u16* W = z == 0 ? Wq : (z == 1 ? Wk : Wv);
  const float* bias = z == 0 ? bq : (z == 1 ? bk : bv);
  u16* out = z == 0 ? Qh : (z == 1 ? Kh : Vt);
  const float sc = z == 0 ? QSCALE : 1.0f;
  const int gm0 = by * 128, gn0 = bx * 128;
  f32x4 acc[4][4] = {};
  gemm_core<4, 4>(A, W, smA, smB, acc, gm0, gn0);

  const int tid = threadIdx.x;
  const int w = tid >> 6, l = tid & 63, g = (l >> 4) & 3, r = l & 15;
  const int wm = w >> 1, wn = w & 1;
#pragma unroll
  for (int mt = 0; mt < 4; ++mt) {
#pragma unroll
    for (int nt = 0; nt < 4; ++nt) {
      int ncol = gn0 + wn * 64 + nt * 16 + r;
      int h = ncol >> 6, dk = ncol & 63;
      float bb = bias[ncol];
      int mrow0 = gm0 + wm * 64 + mt * 16 + g * 4;
      int b = mrow0 >> 11, s0 = mrow0 & 2047;
      if (z < 2) {
#pragma unroll
        for (int i = 0; i < 4; ++i)
          out[(((size_t)b * Hh + h) * Ss + s0 + i) * DKc + dk] =
              f2bf((acc[mt][nt][i] + bb) * sc);
      } else {
        ushort4 ov;
        ov.x = f2bf(acc[mt][nt][0] + bb);
        ov.y = f2bf(acc[mt][nt][1] + bb);
        ov.z = f2bf(acc[mt][nt][2] + bb);
        ov.w = f2bf(acc[mt][nt][3] + bb);
        *reinterpret_cast<ushort4*>(
            &out[(((size_t)b * Hh + h) * DKc + dk) * Ss + s0]) = ov;
      }
    }
  }
}

// ---------------- causal flash attention v6 ----------------
// 1024 blocks (one 64-row q-tile each, longest-first per XCD). K staged in LDS
// (4 slots, 128 kv per barrier period); V read DIRECT from global (L2-resident,
// prefetched right after the barrier -> latency hidden under QK^T+softmax).
// LDS 41KB -> 3 blocks/CU (12 waves/CU).
__global__ __launch_bounds__(256, 3) void attn(
    const u16* __restrict__ Qh, const u16* __restrict__ Kh,
    const u16* __restrict__ Vt, u16* __restrict__ Ob) {
  __shared__ u16 smK[4][64 * 64];
  __shared__ u16 smP[4][16 * 72];

  // fid -> xcd (fid&7) owns bh in [4k,4k+4); per-XCD slots walk qt descending
  const int fid = blockIdx.y * 8 + blockIdx.x;
  const int xcd = fid & 7, slot = fid >> 3;         // slot 0..127
  const int bh = xcd * 4 + (slot >> 5);
  const int qt = 31 - (slot & 31);                  // longest-first
  const int bidx = bh >> 4, h = bh & 15;

  const int tid = threadIdx.x, w = tid >> 6, l = tid & 63;
  const int g = (l >> 4) & 3, r = l & 15;

  const u16* Qb = Qh + (size_t)bh * Ss * DKc;
  const u16* Kb = Kh + (size_t)bh * Ss * DKc;
  const u16* Vb = Vt + (size_t)bh * DKc * Ss;
  u16* Pw = smP[w];

  const int srow0 = tid >> 3, schunk = tid & 7;

  auto stage = [&](int sl, int kb) {
#pragma unroll
    for (int j = 0; j < 2; ++j) {
      int row = j * 32 + srow0;
      int c = schunk ^ (row & 7);
      gload_lds16(Kb + (size_t)(kb + row) * DKc + c * 8,
                  smK[sl] + (j * 256 + w * 64) * 8);
    }
  };

  const int ntile = qt + 1;
  const int npair = (ntile + 1) >> 1;
  const int qw = qt * 64 + w * 16;
  const int q = qw + r;                 // this lane's q row

  short8 qf[2];
  qf[0] = *reinterpret_cast<const short8*>(Qb + (size_t)q * DKc + g * 8);
  qf[1] = *reinterpret_cast<const short8*>(Qb + (size_t)q * DKc + 32 + g * 8);

  stage(0, 0);
  if (ntile > 1) stage(1, 64);

  f32x4 o[4] = {};
  float m_s = -3e38f, l_s = 0.f;

  for (int pp = 0; pp < npair; ++pp) {
    const int slotA = (pp & 1) * 2;
    const int kbA = pp * 128;
    const bool hasB = (2 * pp + 1 < ntile);
    const bool diagA = (2 * pp == qt);
    const bool diagB = hasB && (2 * pp + 1 == qt);

    asm volatile("s_waitcnt vmcnt(0)" ::: "memory");
    __builtin_amdgcn_s_barrier();         // pair pp staged; pair pp-1 reads done
    __builtin_amdgcn_sched_barrier(0);
    if (pp + 1 < npair) {
      int nb = ((pp + 1) & 1) * 2;
      stage(nb, kbA + 128);
      if (2 * pp + 3 < ntile) stage(nb + 1, kbA + 192);
    }

    // prefetch V^T fragments for subtile A direct from global (L2-resident)
    short8 vA[8];
#pragma unroll
    for (int ks = 0; ks < 2; ++ks)
#pragma unroll
      for (int dt = 0; dt < 4; ++dt)
        vA[ks * 4 + dt] = *reinterpret_cast<const short8*>(
            Vb + (size_t)(dt * 16 + r) * Ss + kbA + ks * 32 + g * 8);

    // QK^T swapped: sA/sB rows kv, cols q (log2-scaled via QSCALE)
    f32x4 sA[4] = {}, sB[4] = {};
    __builtin_amdgcn_s_setprio(1);
#pragma unroll
    for (int ks = 0; ks < 2; ++ks)
#pragma unroll
      for (int nt = 0; nt < 4; ++nt) {
        int row = nt * 16 + r;
        int ch = (ks * 4 + g) ^ (row & 7);
        short8 kf = *reinterpret_cast<const short8*>(&smK[slotA][row * 64 + ch * 8]);
        sA[nt] = mfma16(kf, qf[ks], sA[nt]);
      }
    __builtin_amdgcn_s_setprio(0);

    short8 vB[8];
    if (hasB) {
#pragma unroll
      for (int ks = 0; ks < 2; ++ks)
#pragma unroll
        for (int dt = 0; dt < 4; ++dt)
          vB[ks * 4 + dt] = *reinterpret_cast<const short8*>(
              Vb + (size_t)(dt * 16 + r) * Ss + kbA + 64 + ks * 32 + g * 8);
      __builtin_amdgcn_s_setprio(1);
#pragma unroll
      for (int ks = 0; ks < 2; ++ks)
#pragma unroll
        for (int nt = 0; nt < 4; ++nt) {
          int row = nt * 16 + r;
          int ch = (ks * 4 + g) ^ (row & 7);
          short8 kf = *reinterpret_cast<const short8*>(&smK[slotA + 1][row * 64 + ch * 8]);
          sB[nt] = mfma16(kf, qf[ks], sB[nt]);
        }
      __builtin_amdgcn_s_setprio(0);
    }

    const int qloc = w * 16 + r;
    if (diagA) {
#pragma unroll
      for (int nt = 0; nt < 4; ++nt)
#pragma unroll
        for (int i = 0; i < 4; ++i)
          if (nt * 16 + g * 4 + i > qloc) sA[nt][i] = -1e30f;
    }
    if (diagB) {
#pragma unroll
      for (int nt = 0; nt < 4; ++nt)
#pragma unroll
        for (int i = 0; i < 4; ++i)
          if (nt * 16 + g * 4 + i > qloc) sB[nt][i] = -1e30f;
    }

    // one max-tree + defer-check per 128 kv
    float mx0 = fmaxf(fmaxf(sA[0][0], sA[0][1]), fmaxf(sA[0][2], sA[0][3]));
    float mx1 = fmaxf(fmaxf(sA[1][0], sA[1][1]), fmaxf(sA[1][2], sA[1][3]));
    float mx2 = fmaxf(fmaxf(sA[2][0], sA[2][1]), fmaxf(sA[2][2], sA[2][3]));
    float mx3 = fmaxf(fmaxf(sA[3][0], sA[3][1]), fmaxf(sA[3][2], sA[3][3]));
    float mx = fmaxf(fmaxf(mx0, mx1), fmaxf(mx2, mx3));
    if (hasB) {
      float nx0 = fmaxf(fmaxf(sB[0][0], sB[0][1]), fmaxf(sB[0][2], sB[0][3]));
      float nx1 = fmaxf(fmaxf(sB[1][0], sB[1][1]), fmaxf(sB[1][2], sB[1][3]));
      float nx2 = fmaxf(fmaxf(sB[2][0], sB[2][1]), fmaxf(sB[2][2], sB[2][3]));
      float nx3 = fmaxf(fmaxf(sB[3][0], sB[3][1]), fmaxf(sB[3][2], sB[3][3]));
      mx = fmaxf(mx, fmaxf(fmaxf(nx0, nx1), fmaxf(nx2, nx3)));
    }

    if (__any(mx > m_s + 8.f)) {          // defer-max (log2 domain, THR=8)
      float mr = fmaxf(mx, __shfl_xor(mx, 16));
      mr = fmaxf(mr, __shfl_xor(mr, 32));
      float mn = fmaxf(m_s, mr);
      float f = __builtin_amdgcn_exp2f(m_s - mn);
      m_s = mn;
      l_s *= f;
#pragma unroll
      for (int dt = 0; dt < 4; ++dt) {
        o[dt][0] *= f; o[dt][1] *= f; o[dt][2] *= f; o[dt][3] *= f;
      }
    }

    // subtile A: P + l, then PV (V from regs)
#pragma unroll
    for (int nt = 0; nt < 4; ++nt) {
      float p0 = __builtin_amdgcn_exp2f(sA[nt][0] - m_s);
      float p1 = __builtin_amdgcn_exp2f(sA[nt][1] - m_s);
      float p2 = __builtin_amdgcn_exp2f(sA[nt][2] - m_s);
      float p3 = __builtin_amdgcn_exp2f(sA[nt][3] - m_s);
      l_s += (p0 + p1) + (p2 + p3);
      *reinterpret_cast<u32*>(&Pw[r * 72 + nt * 16 + g * 4])     = pk_bf16(p0, p1);
      *reinterpret_cast<u32*>(&Pw[r * 72 + nt * 16 + g * 4 + 2]) = pk_bf16(p2, p3);
    }
    __builtin_amdgcn_s_setprio(1);
#pragma unroll
    for (int ks = 0; ks < 2; ++ks) {
      short8 pf = *reinterpret_cast<const short8*>(&Pw[r * 72 + ks * 32 + g * 8]);
#pragma unroll
      for (int dt = 0; dt < 4; ++dt)
        o[dt] = mfma16(vA[ks * 4 + dt], pf, o[dt]);
    }
    __builtin_amdgcn_s_setprio(0);

    // subtile B
    if (hasB) {
#pragma unroll
      for (int nt = 0; nt < 4; ++nt) {
        float p0 = __builtin_amdgcn_exp2f(sB[nt][0] - m_s);
        float p1 = __builtin_amdgcn_exp2f(sB[nt][1] - m_s);
        float p2 = __builtin_amdgcn_exp2f(sB[nt][2] - m_s);
        float p3 = __builtin_amdgcn_exp2f(sB[nt][3] - m_s);
        l_s += (p0 + p1) + (p2 + p3);
        *reinterpret_cast<u32*>(&Pw[r * 72 + nt * 16 + g * 4])     = pk_bf16(p0, p1);
        *reinterpret_cast<u32*>(&Pw[r * 72 + nt * 16 + g * 4 + 2]) = pk_bf16(p2, p3);
      }
      __builtin_amdgcn_s_setprio(1);
#pragma unroll
      for (int ks = 0; ks < 2; ++ks) {
        short8 pf = *reinterpret_cast<const short8*>(&Pw[r * 72 + ks * 32 + g * 8]);
#pragma unroll
        for (int dt = 0; dt < 4; ++dt)
          o[dt] = mfma16(vB[ks * 4 + dt], pf, o[dt]);
      }
      __builtin_amdgcn_s_setprio(0);
    }
  }

  // epilogue: lane (g,r) holds O^T[d = dt*16+g*4+i][q]; reduce partial l across g
  float lt = l_s;
  lt += __shfl_xor(lt, 16);
  lt += __shfl_xor(lt, 32);
  float inv = 1.f / lt;
  size_t ro = ((size_t)bidx * Ss + q) * Dd + h * DKc;
#pragma unroll
  for (int dt = 0; dt < 4; ++dt) {
    ushort4 ov;
    ov.x = f2bf(o[dt][0] * inv);
    ov.y = f2bf(o[dt][1] * inv);
    ov.z = f2bf(o[dt][2] * inv);
    ov.w = f2bf(o[dt][3] * inv);
    *reinterpret_cast<ushort4*>(&Ob[ro + dt * 16 + g * 4]) = ov;
  }
}

// ---------------- output projection: 64x128 tiles (512 blocks), fp32 out + bias ----
__global__ __launch_bounds__(256, 2) void gemm_out(
    const u16* __restrict__ Ob, const u16* __restrict__ Wo,
    const float* __restrict__ bo, float* __restrict__ out) {
  __shared__ u16 smA[3 * 64 * 32], smB[3 * 128 * 32];
  const int flat = blockIdx.y * 8 + blockIdx.x;
  const int nid = (flat & 7) * 64 + (flat >> 3);
  const int bx = nid & 7, by = nid >> 3;
  const int gm0 = by * 64, gn0 = bx * 128;
  f32x4 acc[2][4] = {};
  gemm_core<2, 4>(Ob, Wo, smA, smB, acc, gm0, gn0);

  const int tid = threadIdx.x;
  const int w = tid >> 6, l = tid & 63, g = (l >> 4) & 3, r = l & 15;
  const int wm = w >> 1, wn = w & 1;
#pragma unroll
  for (int mt = 0; mt < 2; ++mt) {
#pragma unroll
    for (int nt = 0; nt < 4; ++nt) {
      int ncol = gn0 + wn * 64 + nt * 16 + r;
      float bb = bo[ncol];
#pragma unroll
      for (int i = 0; i < 4; ++i) {
        int mrow = gm0 + wm * 32 + mt * 16 + g * 4 + i;
        out[(size_t)mrow * Dd + ncol] = acc[mt][nt][i] + bb;
      }
    }
  }
}

extern "C" void kernel_launch(void* const* d_in, const int* in_sizes, int n_in,
                              void* d_out, int out_size, void* d_ws, size_t ws_size,
                              hipStream_t stream) {
  const float* q    = (const float*)d_in[0];
  const float* k    = (const float*)d_in[1];
  const float* v    = (const float*)d_in[2];
  // d_in[3] = mask (causal tril) — handled analytically
  const float* wq_w = (const float*)d_in[4];
  const float* wq_b = (const float*)d_in[5];
  const float* wk_w = (const float*)d_in[6];
  const float* wk_b = (const float*)d_in[7];
  const float* wv_w = (const float*)d_in[8];
  const float* wv_b = (const float*)d_in[9];
  const float* wo_w = (const float*)d_in[10];
  const float* wo_b = (const float*)d_in[11];

  char* ws = (char*)d_ws;
  u16* xq  = (u16*)(ws + 0);
  u16* xk  = (u16*)(ws + 8388608);
  u16* xv  = (u16*)(ws + 16777216);
  u16* Wqb = (u16*)(ws + 25165824);
  u16* Wkb = (u16*)(ws + 27262976);
  u16* Wvb = (u16*)(ws + 29360128);
  u16* Wob = (u16*)(ws + 31457280);
  u16* Qh  = (u16*)(ws + 33554432);
  u16* Kh  = (u16*)(ws + 41943040);
  u16* Vt  = (u16*)(ws + 50331648);
  u16* Ob  = (u16*)(ws + 0);        // alias xq: dead after projections

  CvtArgs ca;
  ca.in[0] = q;    ca.out[0] = xq;  ca.n[0] = 4194304;
  ca.in[1] = k;    ca.out[1] = xk;  ca.n[1] = 4194304;
  ca.in[2] = v;    ca.out[2] = xv;  ca.n[2] = 4194304;
  ca.in[3] = wq_w; ca.out[3] = Wqb; ca.n[3] = 1048576;
  ca.in[4] = wk_w; ca.out[4] = Wkb; ca.n[4] = 1048576;
  ca.in[5] = wv_w; ca.out[5] = Wvb; ca.n[5] = 1048576;
  ca.in[6] = wo_w; ca.out[6] = Wob; ca.n[6] = 1048576;

  cvt_all<<<dim3(4096, 1, 7), 256, 0, stream>>>(ca);
  proj_qkv<<<dim3(8, 32, 3), 256, 0, stream>>>(xq, xk, xv, Wqb, Wkb, Wvb,
                                               wq_b, wk_b, wv_b, Qh, Kh, Vt);
  attn<<<dim3(8, 128), 256, 0, stream>>>(Qh, Kh, Vt, Ob);
  gemm_out<<<dim3(8, 64), 256, 0, stream>>>(Ob, Wob, wo_b, (float*)d_out);
}

// Round 7
// 109.268 us; speedup vs baseline: 1.5470x; 1.5470x over previous
//
#include <hip/hip_runtime.h>

#define DEV __device__ __forceinline__

typedef __attribute__((ext_vector_type(8))) short short8;
typedef __attribute__((ext_vector_type(4))) float f32x4;
typedef __attribute__((ext_vector_type(4))) unsigned int u32x4;
typedef __bf16 bf16x8 __attribute__((ext_vector_type(8)));
typedef unsigned int u32;
typedef unsigned short u16;

constexpr int Bb = 2, Ss = 2048, Dd = 1024, Hh = 16, DKc = 64;
constexpr int Kk = 1024;   // inner dim of all projection GEMMs

// log2(e)/8: folds the 1/sqrt(DK) score scale AND the exp->exp2 conversion into Q
#define QSCALE 0.1803368801111204f

// ---- fp32 <-> bf16 (RNE), no hip_bf16 dependency ----
DEV u16 f2bf(float f) {
  u32 u = __builtin_bit_cast(u32, f);
  u32 r = (u + 0x7fffu + ((u >> 16) & 1u)) >> 16;
  return (u16)r;
}

DEV u32 pk_bf16(float lo, float hi) {
  u32 w;
  asm("v_cvt_pk_bf16_f32 %0, %1, %2" : "=v"(w) : "v"(lo), "v"(hi));
  return w;
}

DEV f32x4 mfma16(short8 a, short8 b, f32x4 c) {
  return __builtin_amdgcn_mfma_f32_16x16x32_bf16(
      __builtin_bit_cast(bf16x8, a), __builtin_bit_cast(bf16x8, b), c, 0, 0, 0);
}

DEV void gload_lds16(const u16* g, u16* lds) {
  __builtin_amdgcn_global_load_lds(
      (const __attribute__((address_space(1))) u32*)g,
      (__attribute__((address_space(3))) u32*)lds, 16, 0, 0);
}

// ---------------- fp32 -> bf16 conversion (weights only now) ----------------
struct CvtArgs {
  const float* in[4];
  u16* out[4];
  int n[4];
};

__global__ __launch_bounds__(256) void cvt_all(CvtArgs a) {
  int z = blockIdx.z;
  int i = (blockIdx.x * 256 + threadIdx.x) * 4;
  if (i >= a.n[z]) return;
  float4 v = *reinterpret_cast<const float4*>(a.in[z] + i);
  ushort4 o;
  o.x = f2bf(v.x); o.y = f2bf(v.y); o.z = f2bf(v.z); o.w = f2bf(v.w);
  *reinterpret_cast<ushort4*>(a.out[z] + i) = o;
}

// ---------------- GEMM core (bf16 A + bf16 B, both gload_lds, triple-buffered) ------
template<int MT, int NT>
DEV void gemm_core(const u16* __restrict__ A, const u16* __restrict__ Bt,
                   u16* smA, u16* smB, f32x4 (&acc)[MT][NT], int gm0, int gn0) {
  constexpr int NSTEP = Kk / 32;
  constexpr int SA = MT * 1024;            // elements per A buffer
  constexpr int SB = NT * 1024;
  constexpr int S = MT / 2 + NT / 2;       // gloads per thread per stage
  const int tid = threadIdx.x;
  const int w = tid >> 6, l = tid & 63;
  const int g = (l >> 4) & 3, r = l & 15;
  const int wm = w >> 1, wn = w & 1;
  const int srow = l >> 2, scol = (l & 3) * 8;  // 16 rows x 32 cols per 1KB chunk

  auto stage = [&](int buf, int kt) {
    int kb = kt * 32;
#pragma unroll
    for (int cc = 0; cc < MT / 2; ++cc) {
      int c = w + cc * 4;
      gload_lds16(A + (size_t)(gm0 + c * 16 + srow) * Kk + kb + scol,
                  smA + buf * SA + c * 512);
    }
#pragma unroll
    for (int cc = 0; cc < NT / 2; ++cc) {
      int c = w + cc * 4;
      gload_lds16(Bt + (size_t)(gn0 + c * 16 + srow) * Kk + kb + scol,
                  smB + buf * SB + c * 512);
    }
  };

  stage(0, 0);
  stage(1, 1);
  for (int kt = 0; kt < NSTEP; ++kt) {
    const int buf = kt % 3;
    if (kt + 1 < NSTEP) {
      if constexpr (S == 4) asm volatile("s_waitcnt vmcnt(4)" ::: "memory");
      else                  asm volatile("s_waitcnt vmcnt(3)" ::: "memory");
    } else {
      asm volatile("s_waitcnt vmcnt(0)" ::: "memory");
    }
    __builtin_amdgcn_s_barrier();           // stage(kt) visible to all waves
    __builtin_amdgcn_sched_barrier(0);
    if (kt + 2 < NSTEP) stage((kt + 2) % 3, kt + 2);

    short8 af[MT], bf_[NT];
#pragma unroll
    for (int t = 0; t < MT; ++t)
      af[t] = *reinterpret_cast<const short8*>(
          smA + buf * SA + (wm * (MT * 16) + t * 16 + r) * 32 + g * 8);
#pragma unroll
    for (int t = 0; t < NT; ++t)
      bf_[t] = *reinterpret_cast<const short8*>(
          smB + buf * SB + (wn * (NT * 16) + t * 16 + r) * 32 + g * 8);
    __builtin_amdgcn_s_setprio(1);
#pragma unroll
    for (int mt = 0; mt < MT; ++mt)
#pragma unroll
      for (int nt = 0; nt < NT; ++nt)
        acc[mt][nt] = mfma16(af[mt], bf_[nt], acc[mt][nt]);
    __builtin_amdgcn_s_setprio(0);
  }
}

// ---------------- GEMM core mix: A fp32 reg-staged (fused cvt), B bf16 gload_lds ----
// A: 2 reg sets, staged 2-ahead; ds_write just before barrier. B: gload 2-ahead.
// One lgkmcnt(0)+s_barrier per step; counted vmcnt drains only B(kt) (in-order
// retirement: compiler's auto-wait for A(kt) regs already drained older ops).
template<int MT, int NT>
DEV void gemm_core_mix(const float* __restrict__ A, const u16* __restrict__ Bt,
                       u16* smA, u16* smB, f32x4 (&acc)[MT][NT], int gm0, int gn0) {
  constexpr int NSTEP = Kk / 32;
  constexpr int SA = MT * 1024, SB = NT * 1024;
  const int tid = threadIdx.x;
  const int w = tid >> 6, l = tid & 63;
  const int g = (l >> 4) & 3, r = l & 15;
  const int wm = w >> 1, wn = w & 1;
  const int srow = l >> 2, scol = (l & 3) * 8;

  float4 a0[MT / 2][2], a1[MT / 2][2];

  auto loadA = [&](float4 (&dst)[MT / 2][2], int kt) {
    int kb = kt * 32;
#pragma unroll
    for (int c = 0; c < MT / 2; ++c) {
      int p = tid + c * 256;               // pair p -> row p>>2, cols (p&3)*8..+7
      const float* src = A + (size_t)(gm0 + (p >> 2)) * Kk + kb + (p & 3) * 8;
      dst[c][0] = *reinterpret_cast<const float4*>(src);
      dst[c][1] = *reinterpret_cast<const float4*>(src + 4);
    }
  };
  auto writeA = [&](float4 (&s)[MT / 2][2], int buf) {
#pragma unroll
    for (int c = 0; c < MT / 2; ++c) {
      int p = tid + c * 256;
      u32x4 wv;
      wv.x = pk_bf16(s[c][0].x, s[c][0].y);
      wv.y = pk_bf16(s[c][0].z, s[c][0].w);
      wv.z = pk_bf16(s[c][1].x, s[c][1].y);
      wv.w = pk_bf16(s[c][1].z, s[c][1].w);
      *reinterpret_cast<u32x4*>(smA + buf * SA + p * 8) = wv;
    }
  };
  auto stageB = [&](int buf, int kt) {
    int kb = kt * 32;
#pragma unroll
    for (int cc = 0; cc < NT / 2; ++cc) {
      int c = w + cc * 4;
      gload_lds16(Bt + (size_t)(gn0 + c * 16 + srow) * Kk + kb + scol,
                  smB + buf * SB + c * 512);
    }
  };

  loadA(a0, 0); stageB(0, 0);
  loadA(a1, 1); stageB(1, 1);
  for (int kt = 0; kt < NSTEP; ++kt) {
    const int bufA = kt & 1, bufB = kt % 3;
    if (kt & 1) { writeA(a1, bufA); if (kt + 2 < NSTEP) loadA(a1, kt + 2); }
    else        { writeA(a0, bufA); if (kt + 2 < NSTEP) loadA(a0, kt + 2); }
    // drain B(kt): leave A(kt+1)[4] + B(kt+1)[2] + A(kt+2)[4] in flight
    if (kt + 2 < NSTEP)      asm volatile("s_waitcnt vmcnt(10)" ::: "memory");
    else if (kt + 1 < NSTEP) asm volatile("s_waitcnt vmcnt(6)" ::: "memory");
    else                     asm volatile("s_waitcnt vmcnt(0)" ::: "memory");
    asm volatile("s_waitcnt lgkmcnt(0)" ::: "memory");
    __builtin_amdgcn_s_barrier();          // writes(kt) + B(kt) visible; reads(kt-1) done
    __builtin_amdgcn_sched_barrier(0);
    if (kt + 2 < NSTEP) stageB((kt + 2) % 3, kt + 2);

    short8 af[MT], bf_[NT];
#pragma unroll
    for (int t = 0; t < MT; ++t)
      af[t] = *reinterpret_cast<const short8*>(
          smA + bufA * SA + (wm * (MT * 16) + t * 16 + r) * 32 + g * 8);
#pragma unroll
    for (int t = 0; t < NT; ++t)
      bf_[t] = *reinterpret_cast<const short8*>(
          smB + bufB * SB + (wn * (NT * 16) + t * 16 + r) * 32 + g * 8);
    __builtin_amdgcn_s_setprio(1);
#pragma unroll
    for (int mt = 0; mt < MT; ++mt)
#pragma unroll
      for (int nt = 0; nt < NT; ++nt)
        acc[mt][nt] = mfma16(af[mt], bf_[nt], acc[mt][nt]);
    __builtin_amdgcn_s_setprio(0);
  }
}

// ---------------- QKV projection: fp32 inputs fused-converted in staging ----------
// z=0 Q (pre-scaled by QSCALE), z=1 K -> (B,H,S,DK); z=2 V -> (B,H,DK,S)
__global__ __launch_bounds__(256, 3) void proj_qkv(
    const float* __restrict__ xq, const float* __restrict__ xk, const float* __restrict__ xv,
    const u16* __restrict__ Wq, const u16* __restrict__ Wk, const u16* __restrict__ Wv,
    const float* __restrict__ bq, const float* __restrict__ bk, const float* __restrict__ bv,
    u16* __restrict__ Qh, u16* __restrict__ Kh, u16* __restrict__ Vt) {
  __shared__ u16 smA[2 * 4096], smB[3 * 4096];
  // XCD-aware: xcd = flat&7 owns 12 (z,by) A-panels; bx walks slowest
  const int flat = (blockIdx.z * 32 + blockIdx.y) * 8 + blockIdx.x;
  const int zby = (flat & 7) * 12 + ((flat >> 3) % 12);
  const int bx = flat / 96;
  const int z = zby >> 5, by = zby & 31;
  const float* A = z == 0 ? xq : (z == 1 ? xk : xv);
  const u16* W = z == 0 ? Wq : (z == 1 ? Wk : Wv);
  const float* bias = z == 0 ? bq : (z == 1 ? bk : bv);
  u16* out = z == 0 ? Qh : (z == 1 ? Kh : Vt);
  const float sc = z == 0 ? QSCALE : 1.0f;
  const int gm0 = by * 128, gn0 = bx * 128;
  f32x4 acc[4][4] = {};
  gemm_core_mix<4, 4>(A, W, smA, smB, acc, gm0, gn0);

  const int tid = threadIdx.x;
  const int w = tid >> 6, l = tid & 63, g = (l >> 4) & 3, r = l & 15;
  const int wm = w >> 1, wn = w & 1;
#pragma unroll
  for (int mt = 0; mt < 4; ++mt) {
#pragma unroll
    for (int nt = 0; nt < 4; ++nt) {
      int ncol = gn0 + wn * 64 + nt * 16 + r;
      int h = ncol >> 6, dk = ncol & 63;
      float bb = bias[ncol];
      int mrow0 = gm0 + wm * 64 + mt * 16 + g * 4;
      int b = mrow0 >> 11, s0 = mrow0 & 2047;
      if (z < 2) {
#pragma unroll
        for (int i = 0; i < 4; ++i)
          out[(((size_t)b * Hh + h) * Ss + s0 + i) * DKc + dk] =
              f2bf((acc[mt][nt][i] + bb) * sc);
      } else {
        ushort4 ov;
        ov.x = f2bf(acc[mt][nt][0] + bb);
        ov.y = f2bf(acc[mt][nt][1] + bb);
        ov.z = f2bf(acc[mt][nt][2] + bb);
        ov.w = f2bf(acc[mt][nt][3] + bb);
        *reinterpret_cast<ushort4*>(
            &out[(((size_t)b * Hh + h) * DKc + dk) * Ss + s0]) = ov;
      }
    }
  }
}

// ---------------- causal flash attention (round-5 verbatim: 128 kv per barrier) -----
__global__ __launch_bounds__(256, 2) void attn(
    const u16* __restrict__ Qh, const u16* __restrict__ Kh,
    const u16* __restrict__ Vt, u16* __restrict__ Ob) {
  __shared__ u16 smK[4][64 * 64];
  __shared__ u16 smV[4][64 * 64];
  __shared__ u16 smP[4][16 * 72];

  const int fid = blockIdx.y * 16 + blockIdx.x;
  const int xcd = fid & 7, slot = fid >> 3;
  const int bh = xcd * 4 + (slot >> 4);
  const int pair = slot & 15;
  const int bidx = bh >> 4, h = bh & 15;

  const int tid = threadIdx.x, w = tid >> 6, l = tid & 63;
  const int g = (l >> 4) & 3, r = l & 15;

  const u16* Qb = Qh + (size_t)bh * Ss * DKc;
  const u16* Kb = Kh + (size_t)bh * Ss * DKc;
  const u16* Vb = Vt + (size_t)bh * DKc * Ss;
  u16* Pw = smP[w];

  const int srow0 = tid >> 3, schunk = tid & 7;

  auto stage = [&](int sl, int kb) {
#pragma unroll
    for (int j = 0; j < 2; ++j) {
      int row = j * 32 + srow0;
      int c = schunk ^ (row & 7);
      u16* dK = smK[sl] + (j * 256 + w * 64) * 8;
      u16* dV = smV[sl] + (j * 256 + w * 64) * 8;
      gload_lds16(Kb + (size_t)(kb + row) * DKc + c * 8, dK);
      gload_lds16(Vb + (size_t)row * Ss + kb + c * 8, dV);
    }
  };

  for (int t2 = 0; t2 < 2; ++t2) {
    const int qt = (t2 == 0) ? (31 - pair) : pair;
    const int ntile = qt + 1;
    const int npair = (ntile + 1) >> 1;
    const int qw = qt * 64 + w * 16;
    const int q = qw + r;

    if (t2) __builtin_amdgcn_s_barrier();

    short8 qf[2];
    qf[0] = *reinterpret_cast<const short8*>(Qb + (size_t)q * DKc + g * 8);
    qf[1] = *reinterpret_cast<const short8*>(Qb + (size_t)q * DKc + 32 + g * 8);

    stage(0, 0);
    if (ntile > 1) stage(1, 64);

    f32x4 o[4] = {};
    float m_s = -3e38f, l_s = 0.f;

    for (int pp = 0; pp < npair; ++pp) {
      const int slotA = (pp & 1) * 2;
      const int kbA = pp * 128;
      const bool hasB = (2 * pp + 1 < ntile);
      const bool diagA = (2 * pp == qt);
      const bool diagB = hasB && (2 * pp + 1 == qt);

      asm volatile("s_waitcnt vmcnt(0)" ::: "memory");
      __builtin_amdgcn_s_barrier();
      __builtin_amdgcn_sched_barrier(0);
      if (pp + 1 < npair) {
        int nb = ((pp + 1) & 1) * 2;
        stage(nb, kbA + 128);
        if (2 * pp + 3 < ntile) stage(nb + 1, kbA + 192);
      }

      f32x4 sA[4] = {}, sB[4] = {};
      __builtin_amdgcn_s_setprio(1);
#pragma unroll
      for (int ks = 0; ks < 2; ++ks)
#pragma unroll
        for (int nt = 0; nt < 4; ++nt) {
          int row = nt * 16 + r;
          int ch = (ks * 4 + g) ^ (row & 7);
          short8 kf = *reinterpret_cast<const short8*>(&smK[slotA][row * 64 + ch * 8]);
          sA[nt] = mfma16(kf, qf[ks], sA[nt]);
        }
      if (hasB) {
#pragma unroll
        for (int ks = 0; ks < 2; ++ks)
#pragma unroll
          for (int nt = 0; nt < 4; ++nt) {
            int row = nt * 16 + r;
            int ch = (ks * 4 + g) ^ (row & 7);
            short8 kf = *reinterpret_cast<const short8*>(&smK[slotA + 1][row * 64 + ch * 8]);
            sB[nt] = mfma16(kf, qf[ks], sB[nt]);
          }
      }
      __builtin_amdgcn_s_setprio(0);

      const int qloc = w * 16 + r;
      if (diagA) {
#pragma unroll
        for (int nt = 0; nt < 4; ++nt)
#pragma unroll
          for (int i = 0; i < 4; ++i)
            if (nt * 16 + g * 4 + i > qloc) sA[nt][i] = -1e30f;
      }
      if (diagB) {
#pragma unroll
        for (int nt = 0; nt < 4; ++nt)
#pragma unroll
          for (int i = 0; i < 4; ++i)
            if (nt * 16 + g * 4 + i > qloc) sB[nt][i] = -1e30f;
      }

      float mx0 = fmaxf(fmaxf(sA[0][0], sA[0][1]), fmaxf(sA[0][2], sA[0][3]));
      float mx1 = fmaxf(fmaxf(sA[1][0], sA[1][1]), fmaxf(sA[1][2], sA[1][3]));
      float mx2 = fmaxf(fmaxf(sA[2][0], sA[2][1]), fmaxf(sA[2][2], sA[2][3]));
      float mx3 = fmaxf(fmaxf(sA[3][0], sA[3][1]), fmaxf(sA[3][2], sA[3][3]));
      float mx = fmaxf(fmaxf(mx0, mx1), fmaxf(mx2, mx3));
      if (hasB) {
        float nx0 = fmaxf(fmaxf(sB[0][0], sB[0][1]), fmaxf(sB[0][2], sB[0][3]));
        float nx1 = fmaxf(fmaxf(sB[1][0], sB[1][1]), fmaxf(sB[1][2], sB[1][3]));
        float nx2 = fmaxf(fmaxf(sB[2][0], sB[2][1]), fmaxf(sB[2][2], sB[2][3]));
        float nx3 = fmaxf(fmaxf(sB[3][0], sB[3][1]), fmaxf(sB[3][2], sB[3][3]));
        mx = fmaxf(mx, fmaxf(fmaxf(nx0, nx1), fmaxf(nx2, nx3)));
      }

      if (__any(mx > m_s + 8.f)) {          // defer-max (log2 domain, THR=8)
        float mr = fmaxf(mx, __shfl_xor(mx, 16));
        mr = fmaxf(mr, __shfl_xor(mr, 32));
        float mn = fmaxf(m_s, mr);
        float f = __builtin_amdgcn_exp2f(m_s - mn);
        m_s = mn;
        l_s *= f;
#pragma unroll
        for (int dt = 0; dt < 4; ++dt) {
          o[dt][0] *= f; o[dt][1] *= f; o[dt][2] *= f; o[dt][3] *= f;
        }
      }

#pragma unroll
      for (int nt = 0; nt < 4; ++nt) {
        float p0 = __builtin_amdgcn_exp2f(sA[nt][0] - m_s);
        float p1 = __builtin_amdgcn_exp2f(sA[nt][1] - m_s);
        float p2 = __builtin_amdgcn_exp2f(sA[nt][2] - m_s);
        float p3 = __builtin_amdgcn_exp2f(sA[nt][3] - m_s);
        l_s += (p0 + p1) + (p2 + p3);
        *reinterpret_cast<u32*>(&Pw[r * 72 + nt * 16 + g * 4])     = pk_bf16(p0, p1);
        *reinterpret_cast<u32*>(&Pw[r * 72 + nt * 16 + g * 4 + 2]) = pk_bf16(p2, p3);
      }
      __builtin_amdgcn_s_setprio(1);
#pragma unroll
      for (int ks = 0; ks < 2; ++ks) {
        short8 pf = *reinterpret_cast<const short8*>(&Pw[r * 72 + ks * 32 + g * 8]);
#pragma unroll
        for (int dt = 0; dt < 4; ++dt) {
          int row = dt * 16 + r;
          int ch = (ks * 4 + g) ^ (row & 7);
          short8 vf = *reinterpret_cast<const short8*>(&smV[slotA][row * 64 + ch * 8]);
          o[dt] = mfma16(vf, pf, o[dt]);
        }
      }
      __builtin_amdgcn_s_setprio(0);

      if (hasB) {
#pragma unroll
        for (int nt = 0; nt < 4; ++nt) {
          float p0 = __builtin_amdgcn_exp2f(sB[nt][0] - m_s);
          float p1 = __builtin_amdgcn_exp2f(sB[nt][1] - m_s);
          float p2 = __builtin_amdgcn_exp2f(sB[nt][2] - m_s);
          float p3 = __builtin_amdgcn_exp2f(sB[nt][3] - m_s);
          l_s += (p0 + p1) + (p2 + p3);
          *reinterpret_cast<u32*>(&Pw[r * 72 + nt * 16 + g * 4])     = pk_bf16(p0, p1);
          *reinterpret_cast<u32*>(&Pw[r * 72 + nt * 16 + g * 4 + 2]) = pk_bf16(p2, p3);
        }
        __builtin_amdgcn_s_setprio(1);
#pragma unroll
        for (int ks = 0; ks < 2; ++ks) {
          short8 pf = *reinterpret_cast<const short8*>(&Pw[r * 72 + ks * 32 + g * 8]);
#pragma unroll
          for (int dt = 0; dt < 4; ++dt) {
            int row = dt * 16 + r;
            int ch = (ks * 4 + g) ^ (row & 7);
            short8 vf = *reinterpret_cast<const short8*>(&smV[slotA + 1][row * 64 + ch * 8]);
            o[dt] = mfma16(vf, pf, o[dt]);
          }
        }
        __builtin_amdgcn_s_setprio(0);
      }
    }

    float lt = l_s;
    lt += __shfl_xor(lt, 16);
    lt += __shfl_xor(lt, 32);
    float inv = 1.f / lt;
    size_t ro = ((size_t)bidx * Ss + q) * Dd + h * DKc;
#pragma unroll
    for (int dt = 0; dt < 4; ++dt) {
      ushort4 ov;
      ov.x = f2bf(o[dt][0] * inv);
      ov.y = f2bf(o[dt][1] * inv);
      ov.z = f2bf(o[dt][2] * inv);
      ov.w = f2bf(o[dt][3] * inv);
      *reinterpret_cast<ushort4*>(&Ob[ro + dt * 16 + g * 4]) = ov;
    }
  }
}

// ---------------- output projection: 64x128 tiles, fp32 out + bias ----------------
__global__ __launch_bounds__(256, 2) void gemm_out(
    const u16* __restrict__ Ob, const u16* __restrict__ Wo,
    const float* __restrict__ bo, float* __restrict__ out) {
  __shared__ u16 smA[3 * 64 * 32], smB[3 * 128 * 32];
  // XCD-aware: xcd owns 8 adjacent A-panels (by); bx walks slowest
  const int flat = blockIdx.y * 8 + blockIdx.x;
  const int by = (flat & 7) * 8 + ((flat >> 3) & 7);
  const int bx = flat >> 6;
  const int gm0 = by * 64, gn0 = bx * 128;
  f32x4 acc[2][4] = {};
  gemm_core<2, 4>(Ob, Wo, smA, smB, acc, gm0, gn0);

  const int tid = threadIdx.x;
  const int w = tid >> 6, l = tid & 63, g = (l >> 4) & 3, r = l & 15;
  const int wm = w >> 1, wn = w & 1;
#pragma unroll
  for (int mt = 0; mt < 2; ++mt) {
#pragma unroll
    for (int nt = 0; nt < 4; ++nt) {
      int ncol = gn0 + wn * 64 + nt * 16 + r;
      float bb = bo[ncol];
#pragma unroll
      for (int i = 0; i < 4; ++i) {
        int mrow = gm0 + wm * 32 + mt * 16 + g * 4 + i;
        out[(size_t)mrow * Dd + ncol] = acc[mt][nt][i] + bb;
      }
    }
  }
}

extern "C" void kernel_launch(void* const* d_in, const int* in_sizes, int n_in,
                              void* d_out, int out_size, void* d_ws, size_t ws_size,
                              hipStream_t stream) {
  const float* q    = (const float*)d_in[0];
  const float* k    = (const float*)d_in[1];
  const float* v    = (const float*)d_in[2];
  // d_in[3] = mask (causal tril) — handled analytically
  const float* wq_w = (const float*)d_in[4];
  const float* wq_b = (const float*)d_in[5];
  const float* wk_w = (const float*)d_in[6];
  const float* wk_b = (const float*)d_in[7];
  const float* wv_w = (const float*)d_in[8];
  const float* wv_b = (const float*)d_in[9];
  const float* wo_w = (const float*)d_in[10];
  const float* wo_b = (const float*)d_in[11];

  char* ws = (char*)d_ws;
  u16* Wqb = (u16*)(ws + 25165824);
  u16* Wkb = (u16*)(ws + 27262976);
  u16* Wvb = (u16*)(ws + 29360128);
  u16* Wob = (u16*)(ws + 31457280);
  u16* Qh  = (u16*)(ws + 33554432);
  u16* Kh  = (u16*)(ws + 41943040);
  u16* Vt  = (u16*)(ws + 50331648);
  u16* Ob  = (u16*)(ws + 0);

  CvtArgs ca;
  ca.in[0] = wq_w; ca.out[0] = Wqb; ca.n[0] = 1048576;
  ca.in[1] = wk_w; ca.out[1] = Wkb; ca.n[1] = 1048576;
  ca.in[2] = wv_w; ca.out[2] = Wvb; ca.n[2] = 1048576;
  ca.in[3] = wo_w; ca.out[3] = Wob; ca.n[3] = 1048576;

  cvt_all<<<dim3(1024, 1, 4), 256, 0, stream>>>(ca);
  proj_qkv<<<dim3(8, 32, 3), 256, 0, stream>>>(q, k, v, Wqb, Wkb, Wvb,
                                               wq_b, wk_b, wv_b, Qh, Kh, Vt);
  attn<<<dim3(16, 32), 256, 0, stream>>>(Qh, Kh, Vt, Ob);
  gemm_out<<<dim3(8, 64), 256, 0, stream>>>(Ob, Wob, wo_b, (float*)d_out);
}